// Round 16
// baseline (1610.472 us; speedup 1.0000x reference)
//
#include <hip/hip_runtime.h>

typedef unsigned short u16;
typedef unsigned int   u32;
typedef _Float16 f16;
typedef __attribute__((ext_vector_type(8))) unsigned short u16x8;
typedef __attribute__((ext_vector_type(8))) _Float16 f16x8;
typedef __attribute__((ext_vector_type(2))) _Float16 f16x2;
typedef __attribute__((ext_vector_type(4))) float f32x4;

__device__ __forceinline__ u16 f2h(float f) {
  f16 h = (f16)f;
  return __builtin_bit_cast(u16, h);
}
__device__ __forceinline__ float h2f(u16 u) {
  return (float)__builtin_bit_cast(f16, u);
}

// ---------------- weight prep: transpose to (N x K) row-major + cvt f16 -----
__global__ __launch_bounds__(256) void prep_w(const float* __restrict__ Wq,
    const float* __restrict__ Wk, const float* __restrict__ Wv,
    const float* __restrict__ f0, const float* __restrict__ f1,
    u16* __restrict__ wt) {
  int t = blockIdx.x * 256 + threadIdx.x;
  float v;
  if (t < 786432) {
    int i = t >> 18, r = t & 262143, n = r >> 9, k = r & 511;
    v = Wq[(size_t)(i << 18) + k * 512 + n];
  } else if (t < 2359296) {
    int r = t - 786432, i = r >> 19, r2 = r & 524287;
    int n = (r2 >> 9) & 511, k = r2 & 511;
    v = ((r2 >> 18) ? Wv : Wk)[(size_t)(i << 18) + k * 512 + n];
  } else if (t < 2883584) {
    int r = t - 2359296, n = r >> 9, k = r & 511;
    v = f0[(size_t)k * 1024 + n];
  } else {
    int r = t - 2883584, n = r >> 9, k = r & 511;
    v = f1[(size_t)k * 1024 + n];
  }
  wt[t] = f2h(v);
}

// ---------------- LayerNorm (fp32 in) -> xn f16, xb f16(raw) ----------------
__global__ __launch_bounds__(256) void ln_f32(const float* __restrict__ x,
    const float* __restrict__ g, const float* __restrict__ bta,
    u16* __restrict__ xn, u16* __restrict__ xb) {
  int row = (blockIdx.x << 2) + (threadIdx.x >> 6);
  int lane = threadIdx.x & 63;
  const float* xr = x + (size_t)row * 512 + (lane << 3);
  float4 a = *(const float4*)xr;
  float4 c = *(const float4*)(xr + 4);
  float v[8] = {a.x, a.y, a.z, a.w, c.x, c.y, c.z, c.w};
  float s = 0.f, s2 = 0.f;
#pragma unroll
  for (int j = 0; j < 8; ++j) { s += v[j]; s2 += v[j] * v[j]; }
  for (int off = 32; off; off >>= 1) { s += __shfl_xor(s, off); s2 += __shfl_xor(s2, off); }
  float mean = s * (1.f / 512.f);
  float var = s2 * (1.f / 512.f) - mean * mean;
  float rs = rsqrtf(var + 1e-5f);
  const float* gp = g + (lane << 3);
  const float* bp = bta + (lane << 3);
  u16x8 pb, pn;
#pragma unroll
  for (int j = 0; j < 8; ++j) {
    pb[j] = f2h(v[j]);
    pn[j] = f2h((v[j] - mean) * rs * gp[j] + bp[j]);
  }
  *(u16x8*)(xb + (size_t)row * 512 + (lane << 3)) = pb;
  *(u16x8*)(xn + (size_t)row * 512 + (lane << 3)) = pn;
}

// ---------------- LayerNorm (f16 in) -> f16 out -----------------------------
__global__ __launch_bounds__(256) void ln_b16(const u16* __restrict__ xin,
    const float* __restrict__ g, const float* __restrict__ bta,
    u16* __restrict__ xout) {
  int row = (blockIdx.x << 2) + (threadIdx.x >> 6);
  int lane = threadIdx.x & 63;
  f16x8 u = *(const f16x8*)(xin + (size_t)row * 512 + (lane << 3));
  float v[8];
#pragma unroll
  for (int j = 0; j < 8; ++j) v[j] = (float)u[j];
  float s = 0.f, s2 = 0.f;
#pragma unroll
  for (int j = 0; j < 8; ++j) { s += v[j]; s2 += v[j] * v[j]; }
  for (int off = 32; off; off >>= 1) { s += __shfl_xor(s, off); s2 += __shfl_xor(s2, off); }
  float mean = s * (1.f / 512.f);
  float var = s2 * (1.f / 512.f) - mean * mean;
  float rs = rsqrtf(var + 1e-5f);
  const float* gp = g + (lane << 3);
  const float* bp = bta + (lane << 3);
  u16x8 pn;
#pragma unroll
  for (int j = 0; j < 8; ++j) pn[j] = f2h((v[j] - mean) * rs * gp[j] + bp[j]);
  *(u16x8*)(xout + (size_t)row * 512 + (lane << 3)) = pn;
}

// ---------------- GEMM: C(MxN f16) = A(Mx512 f16) * Bt(Nx512 f16)^T ---------
// 128x128 tile, BK=32, 4 waves, DOUBLE-BUFFERED with counted vmcnt, and
// ZERO occupancy cost: Cs epilogue union (34.8KB) dominates LDS, so dbuf
// A/B (4x8KB=32KB) fits underneath -> still 4 blocks/CU (R14's winning
// occupancy) + true stage/compute overlap (the cell the R10-R13 ledger
// never tested: every prior pipeline paid LDS->occupancy).
// Schedule/step: issue stage(t+1) -> vmcnt(4) [drains stage(t) ONLY;
// stage(t+1) flies through compute] -> barrier -> compute(t) -> barrier.
// Bank-optimal swizzle for BK=32 (row=64B): slot ^= (row>>1)&3 over 4
// 16B slots, applied on global source col + fragment read (rule #21).
template <bool GELU>
__global__ __launch_bounds__(256, 4) void gemm_bt(const u16* __restrict__ A,
    const u16* __restrict__ Bt, u16* __restrict__ C,
    const float* __restrict__ bias, int M, int N) {
  __shared__ __align__(16) char smem[34816];  // A0|A1 8K each, B0|B1 8K each; Cs union
  u16* Cs = (u16*)smem;                       // 128 x 136 f16, after final barrier
  constexpr int LDC = 136;
  int tid = threadIdx.x;
  int w = tid >> 6, lane = tid & 63;
  int nwg = gridDim.x * gridDim.y;
  int wg = blockIdx.x + gridDim.x * blockIdx.y;
  int swz = (wg & 7) * (nwg >> 3) + (wg >> 3);
  int m0 = (swz / gridDim.x) << 7, n0 = (swz % gridDim.x) << 7;
  int wm = (w & 1) << 6, wn = (w >> 1) << 6;
  f32x4 acc[4][4] = {};
  const int grow2 = tid >> 2;                 // 0..63 (row base within sweep)
  const int gcol = (((tid & 3) ^ ((grow2 >> 1) & 3)) << 3);  // pre-swizzled col
  // stage K-tile kt (32 cols) into buffer bi: A at bi*8K, B at 16K+bi*8K
#define GSTAGE(kt, bi)                                                          \
  {                                                                             \
    u16* dA = (u16*)(smem + ((bi) << 13));                                      \
    u16* dB = (u16*)(smem + 16384 + ((bi) << 13));                              \
    _Pragma("unroll")                                                           \
    for (int s = 0; s < 2; ++s) {                                               \
      const u16* gA = A + (size_t)(m0 + grow2 + (s << 6)) * 512 + ((kt) << 5) + gcol; \
      __builtin_amdgcn_global_load_lds(                                         \
          (const __attribute__((address_space(1))) u32*)gA,                     \
          (__attribute__((address_space(3))) u32*)(dA + tid * 8 + (s << 11)), 16, 0, 0); \
    }                                                                           \
    _Pragma("unroll")                                                           \
    for (int s = 0; s < 2; ++s) {                                               \
      const u16* gB = Bt + (size_t)(n0 + grow2 + (s << 6)) * 512 + ((kt) << 5) + gcol; \
      __builtin_amdgcn_global_load_lds(                                         \
          (const __attribute__((address_space(1))) u32*)gB,                     \
          (__attribute__((address_space(3))) u32*)(dB + tid * 8 + (s << 11)), 16, 0, 0); \
    }                                                                           \
  }
  GSTAGE(0, 0);
  const int sw_lane = ((lane & 15) >> 1) & 3;  // (rr>>1)&3 is uniform in mi/ni
  for (int kt = 0; kt < 16; ++kt) {
    if (kt + 1 < 16) {
      GSTAGE(kt + 1, (kt + 1) & 1);           // flies through compute(kt)
      asm volatile("s_waitcnt vmcnt(4)" ::: "memory");   // stage(kt) done (mine)
    } else {
      asm volatile("s_waitcnt vmcnt(0)" ::: "memory");
    }
    __syncthreads();                          // stage(kt) done (all waves)
    const u16* As = (const u16*)(smem + ((kt & 1) << 13));
    const u16* Bs = (const u16*)(smem + 16384 + ((kt & 1) << 13));
    {
      int slot_w = lane >> 4;                 // 16B slot 0..3 (K-quarter)
      int sl = (slot_w ^ sw_lane) << 3;
      f16x8 af[4], bfr[4];
#pragma unroll
      for (int mi = 0; mi < 4; ++mi) {
        int rr = wm + (mi << 4) + (lane & 15);
        af[mi] = *(const f16x8*)(As + (rr << 5) + sl);
      }
#pragma unroll
      for (int ni = 0; ni < 4; ++ni) {
        int rr = wn + (ni << 4) + (lane & 15);
        bfr[ni] = *(const f16x8*)(Bs + (rr << 5) + sl);
      }
#pragma unroll
      for (int mi = 0; mi < 4; ++mi)
#pragma unroll
        for (int ni = 0; ni < 4; ++ni)
          acc[mi][ni] = __builtin_amdgcn_mfma_f32_16x16x32_f16(af[mi], bfr[ni], acc[mi][ni], 0, 0, 0);
    }
    __syncthreads();                          // compute(kt) done -> buf reusable
  }
#undef GSTAGE
  // ---- LDS-staged epilogue: acc -> Cs (f16) -> coalesced streaming stores
  int cr = (lane >> 4) << 2, cc = lane & 15;
#pragma unroll
  for (int mi = 0; mi < 4; ++mi) {
#pragma unroll
    for (int ni = 0; ni < 4; ++ni) {
      float bv = 0.f;
      if (GELU) bv = bias[n0 + wn + (ni << 4) + cc];
#pragma unroll
      for (int j = 0; j < 4; ++j) {
        float v = acc[mi][ni][j];
        if (GELU) { v += bv; v = 0.5f * v * (1.f + erff(v * 0.70710678118f)); }
        Cs[(wm + (mi << 4) + cr + j) * LDC + wn + (ni << 4) + cc] = f2h(v);
      }
    }
  }
  __syncthreads();
  int r = tid >> 1, hc = (tid & 1) << 6;
  u16* crow = C + (size_t)(m0 + r) * N + n0 + hc;
  const u16* srow = Cs + r * LDC + hc;
#pragma unroll
  for (int i = 0; i < 8; ++i)
    *(u16x8*)(crow + (i << 3)) = *(const u16x8*)(srow + (i << 3));
}

// ---------------- attention: G batches/block, packed-f16 math ---------------
// (unchanged from R15: grid-filled occupancy, dbuf for 12/7, single-buf 25)
// PMODE: 0 out=xb+o/(3s) | 1 out+=o/(3s) | 2 p=o/s | 3 p+=o/s | 4 out=xb+(p+o/s)/3
template <int NKV, int PMODE, int MINW, int G, bool DBUF>
__global__ __launch_bounds__(512, MINW) void attn(const u16* __restrict__ Q,
    const u16* __restrict__ KV, const u16* __restrict__ xb,
    float* __restrict__ out, u16* __restrict__ p) {
  constexpr int ELEMS = NKV * 1024;
  __shared__ __align__(16) u16 KVl[(DBUF ? 2 : 1)][ELEMS];
  int tid = threadIdx.x;
  int b0 = blockIdx.x * G;
  int h = tid >> 6, r = tid & 63, n = r >> 1, half = r & 1;
  int dbase = (h << 6) + (half << 5);
  bool act = (n < 25);
  f16x8 q8[4];
  if constexpr (DBUF) {
    if (act) {
      const u16* qr = Q + (size_t)(b0 * 25 + n) * 512 + dbase;
#pragma unroll
      for (int i = 0; i < 4; ++i) q8[i] = *(const f16x8*)(qr + (i << 3));
    }
    __builtin_amdgcn_sched_barrier(0);
    const u16* src = KV + (size_t)b0 * ELEMS;
    for (int e = tid * 8; e < ELEMS; e += 4096)
      __builtin_amdgcn_global_load_lds(
          (const __attribute__((address_space(1))) u32*)(src + e),
          (__attribute__((address_space(3))) u32*)(KVl[0] + e), 16, 0, 0);
    asm volatile("s_waitcnt vmcnt(0)" ::: "memory");
    __syncthreads();
  }
  for (int t = 0; t < G; ++t) {
    const u16* KVc = KVl[DBUF ? (t & 1) : 0];
    int b = b0 + t;
    size_t rowoff = (size_t)(b * 25 + n) * 512 + dbase;
    f16x8 pv16[4];
    f16x8 xv16[4];
    float4 ov[8];
    if (act) {
      if (PMODE == 3 || PMODE == 4) {
        const u16* prow = p + rowoff;
#pragma unroll
        for (int i = 0; i < 4; ++i) pv16[i] = *(const f16x8*)(prow + (i << 3));
      }
      if (PMODE == 0 || PMODE == 4) {
        const u16* xrow = xb + rowoff;
#pragma unroll
        for (int i = 0; i < 4; ++i) xv16[i] = *(const f16x8*)(xrow + (i << 3));
      }
      if (PMODE == 1) {
        const float* orow = out + rowoff;
#pragma unroll
        for (int i = 0; i < 8; ++i) ov[i] = *(const float4*)(orow + (i << 2));
      }
    }
    f16x8 qn[4];
    if constexpr (DBUF) {
      if (act && t + 1 < G) {
        const u16* qr = Q + (size_t)((b + 1) * 25 + n) * 512 + dbase;
#pragma unroll
        for (int i = 0; i < 4; ++i) qn[i] = *(const f16x8*)(qr + (i << 3));
      }
      __builtin_amdgcn_sched_barrier(0);
      if (t + 1 < G) {
        const u16* src = KV + (size_t)(b + 1) * ELEMS;
        u16* dst = KVl[(t + 1) & 1];
        for (int e = tid * 8; e < ELEMS; e += 4096)
          __builtin_amdgcn_global_load_lds(
              (const __attribute__((address_space(1))) u32*)(src + e),
              (__attribute__((address_space(3))) u32*)(dst + e), 16, 0, 0);
      }
    } else {
      if (act) {
        const u16* qr = Q + (size_t)(b * 25 + n) * 512 + dbase;
#pragma unroll
        for (int i = 0; i < 4; ++i) q8[i] = *(const f16x8*)(qr + (i << 3));
      }
      const u16* src = KV + (size_t)b * ELEMS;
      for (int e = tid * 8; e < ELEMS; e += 4096)
        __builtin_amdgcn_global_load_lds(
            (const __attribute__((address_space(1))) u32*)(src + e),
            (__attribute__((address_space(3))) u32*)(KVl[0] + e), 16, 0, 0);
      asm volatile("s_waitcnt vmcnt(0)" ::: "memory");
      __syncthreads();
    }
    if (act) {
      const f16x2* q2 = (const f16x2*)q8;
      float s[NKV];
      float mx = -1e30f;
#pragma unroll
      for (int m = 0; m < NKV; ++m) {
        const u16* kr = KVc + m * 1024 + dbase;
        f16x2 a0 = {(f16)0.f, (f16)0.f}, a1 = a0;
#pragma unroll
        for (int i = 0; i < 4; ++i) {
          f16x8 kv = *(const f16x8*)(kr + (i << 3));
          const f16x2* k2 = (const f16x2*)&kv;
          a0 += q2[i * 4 + 0] * k2[0];
          a1 += q2[i * 4 + 1] * k2[1];
          a0 += q2[i * 4 + 2] * k2[2];
          a1 += q2[i * 4 + 3] * k2[3];
        }
        f16x2 at = a0 + a1;
        float d = (float)at[0] + (float)at[1];
        d += __shfl_xor(d, 1);
        s[m] = d * 0.125f;
        mx = fmaxf(mx, s[m]);
      }
      float sum = 0.f;
#pragma unroll
      for (int m = 0; m < NKV; ++m) { s[m] = __expf(s[m] - mx); sum += s[m]; }
      f16x8 o8[4] = {};
#pragma unroll
      for (int m = 0; m < NKV; ++m) {
        f16 ah = (f16)s[m];
        f16x8 av = {ah, ah, ah, ah, ah, ah, ah, ah};
        const u16* vr = KVc + m * 1024 + 512 + dbase;
#pragma unroll
        for (int i = 0; i < 4; ++i) {
          f16x8 vv = *(const f16x8*)(vr + (i << 3));
          o8[i] += vv * av;
        }
      }
      if (PMODE == 0 || PMODE == 1) {
        float sc = (1.f / sum) * (1.f / 3.f);
        float* orow = out + rowoff;
#pragma unroll
        for (int i = 0; i < 4; ++i) {
#pragma unroll
          for (int j = 0; j < 8; j += 4) {
            float4 rr;
            if (PMODE == 0) {
              rr.x = (float)o8[i][j + 0] * sc + (float)xv16[i][j + 0];
              rr.y = (float)o8[i][j + 1] * sc + (float)xv16[i][j + 1];
              rr.z = (float)o8[i][j + 2] * sc + (float)xv16[i][j + 2];
              rr.w = (float)o8[i][j + 3] * sc + (float)xv16[i][j + 3];
            } else {
              float4 pv = ov[i * 2 + (j >> 2)];
              rr.x = (float)o8[i][j + 0] * sc + pv.x;
              rr.y = (float)o8[i][j + 1] * sc + pv.y;
              rr.z = (float)o8[i][j + 2] * sc + pv.z;
              rr.w = (float)o8[i][j + 3] * sc + pv.w;
            }
            *(float4*)(orow + (i << 3) + j) = rr;
          }
        }
      } else if (PMODE == 2 || PMODE == 3) {
        float sc = 1.f / sum;
        u16* prow = p + rowoff;
#pragma unroll
        for (int i = 0; i < 4; ++i) {
          u16x8 pk;
#pragma unroll
          for (int j = 0; j < 8; ++j) {
            float v = (float)o8[i][j] * sc;
            if (PMODE == 3) v += (float)pv16[i][j];
            pk[j] = f2h(v);
          }
          *(u16x8*)(prow + (i << 3)) = pk;
        }
      } else {                                 // PMODE 4
        float sc = 1.f / sum;
        float* orow = out + rowoff;
#pragma unroll
        for (int i = 0; i < 4; ++i) {
#pragma unroll
          for (int j = 0; j < 8; j += 4) {
            float4 rr;
            rr.x = (float)xv16[i][j + 0] + ((float)pv16[i][j + 0] + (float)o8[i][j + 0] * sc) * (1.f / 3.f);
            rr.y = (float)xv16[i][j + 1] + ((float)pv16[i][j + 1] + (float)o8[i][j + 1] * sc) * (1.f / 3.f);
            rr.z = (float)xv16[i][j + 2] + ((float)pv16[i][j + 2] + (float)o8[i][j + 2] * sc) * (1.f / 3.f);
            rr.w = (float)xv16[i][j + 3] + ((float)pv16[i][j + 3] + (float)o8[i][j + 3] * sc) * (1.f / 3.f);
            *(float4*)(orow + (i << 3) + j) = rr;
          }
        }
      }
    }
    if constexpr (DBUF) {
      asm volatile("s_waitcnt vmcnt(0)" ::: "memory");
      __syncthreads();
#pragma unroll
      for (int i = 0; i < 4; ++i) q8[i] = qn[i];
    } else {
      if (t + 1 < G) __syncthreads();
    }
  }
}

// ---------------- pool: fc2 + softmax + S^T * l_feat ------------------------
template <int NIN, int NOUT>
__global__ __launch_bounds__(256) void pool(const u16* __restrict__ h,
    const u16* __restrict__ lf, const float* __restrict__ w2,
    const float* __restrict__ b2, u16* __restrict__ lout) {
  __shared__ __align__(16) float W2l[1024 * NOUT];
  __shared__ __align__(16) u16 Xl[NIN * 512];
  __shared__ __align__(16) float Sl[NIN * NOUT];
  int b = blockIdx.x, tid = threadIdx.x;
  for (int e = tid; e < 1024 * NOUT; e += 256) W2l[e] = w2[e];
  for (int e = tid * 8; e < NIN * 512; e += 2048)
    *(u16x8*)(Xl + e) = *(const u16x8*)(lf + (size_t)b * NIN * 512 + e);
  __syncthreads();
  if (tid < NIN * 8) {
    int nn = tid >> 3, sub = tid & 7;
    float pl[NOUT] = {};
    const u16* hr = h + (size_t)(b * NIN + nn) * 1024;
    for (int cc = 0; cc < 128; ++cc) {
      int c = sub + (cc << 3);
      float hv = h2f(hr[c]);
#pragma unroll
      for (int s2 = 0; s2 < NOUT; ++s2) pl[s2] += hv * W2l[c * NOUT + s2];
    }
#pragma unroll
    for (int s2 = 0; s2 < NOUT; ++s2) {
      pl[s2] += __shfl_down(pl[s2], 4, 8);
      pl[s2] += __shfl_down(pl[s2], 2, 8);
      pl[s2] += __shfl_down(pl[s2], 1, 8);
    }
    if (sub == 0) {
      float mx = -1e30f;
#pragma unroll
      for (int s2 = 0; s2 < NOUT; ++s2) { pl[s2] += b2[s2]; mx = fmaxf(mx, pl[s2]); }
      float sum = 0.f;
#pragma unroll
      for (int s2 = 0; s2 < NOUT; ++s2) { pl[s2] = __expf(pl[s2] - mx); sum += pl[s2]; }
      float inv = 1.f / sum;
#pragma unroll
      for (int s2 = 0; s2 < NOUT; ++s2) Sl[nn * NOUT + s2] = pl[s2] * inv;
    }
  }
  __syncthreads();
  int c0 = tid << 1;
#pragma unroll
  for (int s2 = 0; s2 < NOUT; ++s2) {
    float a0 = 0.f, a1 = 0.f;
#pragma unroll
    for (int nn = 0; nn < NIN; ++nn) {
      float wv = Sl[nn * NOUT + s2];
      a0 += wv * h2f(Xl[nn * 512 + c0]);
      a1 += wv * h2f(Xl[nn * 512 + c0 + 1]);
    }
    u32 pk = (u32)f2h(a0) | ((u32)f2h(a1) << 16);
    *(u32*)(lout + (size_t)(b * NOUT + s2) * 512 + c0) = pk;
  }
}

// ---------------- launcher ---------------------------------------------------
extern "C" void kernel_launch(void* const* d_in, const int* in_sizes, int n_in,
                              void* d_out, int out_size, void* d_ws, size_t ws_size,
                              hipStream_t stream) {
  const float* src = (const float*)d_in[0];
  const float* g    = (const float*)d_in[2];
  const float* bt   = (const float*)d_in[3];
  const float* Wq   = (const float*)d_in[4];
  const float* Wk   = (const float*)d_in[5];
  const float* Wv   = (const float*)d_in[6];
  const float* f0w  = (const float*)d_in[7];
  const float* f0b  = (const float*)d_in[8];
  const float* f0w2 = (const float*)d_in[9];
  const float* f0b2 = (const float*)d_in[10];
  const float* f1w  = (const float*)d_in[11];
  const float* f1b  = (const float*)d_in[12];
  const float* f1w2 = (const float*)d_in[13];
  const float* f1b2 = (const float*)d_in[14];
  float* out = (float*)d_out;
  char* ws = (char*)d_ws;

  // base layout (bytes), peak 503 MB (validated); pbuf extension to 632 MB
  u16* wt  = (u16*)(ws + 0);
  u16* xn  = (u16*)(ws + 6815744);
  u16* xb  = (u16*)(ws + 111673344);
  u16* qb  = (u16*)(ws + 216530944);
  u16* B1  = (u16*)(ws + 321388544);
  u16* l1  = (u16*)(ws + 426246144);
  u16* kn1 = (u16*)(ws + 476577792);
  u16* l2  = qb;
  u16* kn2 = qb + 14680064;
  bool bigws = ws_size >= 640000000ull;
  u16* pbuf = (u16*)(ws + 526909440);

  prep_w<<<13312, 256, 0, stream>>>(Wq, Wk, Wv, f0w, f1w, wt);
  ln_f32<<<25600, 256, 0, stream>>>(src, g, bt, xn, xb);

  // scale 0
  gemm_bt<false><<<dim3(4, 800), 256, 0, stream>>>(xn, wt, qb, nullptr, 102400, 512);
  for (int s = 0; s < 2; ++s) {
    size_t ro = (size_t)s * 51200;
    gemm_bt<false><<<dim3(8, 400), 256, 0, stream>>>(xn + ro * 512, wt + 786432, B1, nullptr, 51200, 1024);
    if (bigws)
      attn<25, 2, 3, 2, false><<<1024, 512, 0, stream>>>(qb + ro * 512, B1, xb + ro * 512, out + ro * 512, pbuf + ro * 512);
    else
      attn<25, 0, 3, 2, false><<<1024, 512, 0, stream>>>(qb + ro * 512, B1, xb + ro * 512, out + ro * 512, pbuf);
  }

  // pool 0
  for (int s = 0; s < 2; ++s) {
    size_t ro = (size_t)s * 51200;
    gemm_bt<true><<<dim3(8, 400), 256, 0, stream>>>(xb + ro * 512, wt + 2359296, B1, f0b, 51200, 1024);
    pool<25, 12><<<2048, 256, 0, stream>>>(B1, xb + ro * 512, f0w2, f0b2, l1 + (size_t)s * 2048 * 12 * 512);
  }
  ln_b16<<<12288, 256, 0, stream>>>(l1, g, bt, kn1);

  // scale 1
  gemm_bt<false><<<dim3(4, 800), 256, 0, stream>>>(xn, wt + 262144, qb, nullptr, 102400, 512);
  gemm_bt<false><<<dim3(8, 384), 256, 0, stream>>>(kn1, wt + 786432 + 524288, B1, nullptr, 49152, 1024);
  if (bigws)
    attn<12, 3, 3, 4, true><<<1024, 512, 0, stream>>>(qb, B1, xb, out, pbuf);
  else
    attn<12, 1, 3, 4, true><<<1024, 512, 0, stream>>>(qb, B1, xb, out, pbuf);

  // pool 1
  gemm_bt<true><<<dim3(8, 384), 256, 0, stream>>>(l1, wt + 2883584, B1, f1b, 49152, 1024);
  pool<12, 7><<<4096, 256, 0, stream>>>(B1, l1, f1w2, f1b2, l2);
  ln_b16<<<7168, 256, 0, stream>>>(l2, g, bt, kn2);

  // scale 2 (KV gemm before Q gemm: kn2 lives in qb region)
  gemm_bt<false><<<dim3(8, 224), 256, 0, stream>>>(kn2, wt + 786432 + 1048576, B1, nullptr, 28672, 1024);
  gemm_bt<false><<<dim3(4, 800), 256, 0, stream>>>(xn, wt + 524288, qb, nullptr, 102400, 512);
  if (bigws)
    attn<7, 4, 3, 4, true><<<1024, 512, 0, stream>>>(qb, B1, xb, out, pbuf);
  else
    attn<7, 1, 3, 4, true><<<1024, 512, 0, stream>>>(qb, B1, xb, out, pbuf);
}

// Round 17
// 1533.044 us; speedup vs baseline: 1.0505x; 1.0505x over previous
//
#include <hip/hip_runtime.h>

typedef unsigned short u16;
typedef unsigned int   u32;
typedef _Float16 f16;
typedef __attribute__((ext_vector_type(8))) unsigned short u16x8;
typedef __attribute__((ext_vector_type(8))) _Float16 f16x8;
typedef __attribute__((ext_vector_type(2))) _Float16 f16x2;
typedef __attribute__((ext_vector_type(4))) float f32x4;

__device__ __forceinline__ u16 f2h(float f) {
  f16 h = (f16)f;
  return __builtin_bit_cast(u16, h);
}
__device__ __forceinline__ float h2f(u16 u) {
  return (float)__builtin_bit_cast(f16, u);
}

// ---------------- weight prep: transpose to (N x K) row-major + cvt f16 -----
__global__ __launch_bounds__(256) void prep_w(const float* __restrict__ Wq,
    const float* __restrict__ Wk, const float* __restrict__ Wv,
    const float* __restrict__ f0, const float* __restrict__ f1,
    u16* __restrict__ wt) {
  int t = blockIdx.x * 256 + threadIdx.x;
  float v;
  if (t < 786432) {
    int i = t >> 18, r = t & 262143, n = r >> 9, k = r & 511;
    v = Wq[(size_t)(i << 18) + k * 512 + n];
  } else if (t < 2359296) {
    int r = t - 786432, i = r >> 19, r2 = r & 524287;
    int n = (r2 >> 9) & 511, k = r2 & 511;
    v = ((r2 >> 18) ? Wv : Wk)[(size_t)(i << 18) + k * 512 + n];
  } else if (t < 2883584) {
    int r = t - 2359296, n = r >> 9, k = r & 511;
    v = f0[(size_t)k * 1024 + n];
  } else {
    int r = t - 2883584, n = r >> 9, k = r & 511;
    v = f1[(size_t)k * 1024 + n];
  }
  wt[t] = f2h(v);
}

// ---------------- LayerNorm (fp32 in) -> xn f16, xb f16(raw) ----------------
__global__ __launch_bounds__(256) void ln_f32(const float* __restrict__ x,
    const float* __restrict__ g, const float* __restrict__ bta,
    u16* __restrict__ xn, u16* __restrict__ xb) {
  int row = (blockIdx.x << 2) + (threadIdx.x >> 6);
  int lane = threadIdx.x & 63;
  const float* xr = x + (size_t)row * 512 + (lane << 3);
  float4 a = *(const float4*)xr;
  float4 c = *(const float4*)(xr + 4);
  float v[8] = {a.x, a.y, a.z, a.w, c.x, c.y, c.z, c.w};
  float s = 0.f, s2 = 0.f;
#pragma unroll
  for (int j = 0; j < 8; ++j) { s += v[j]; s2 += v[j] * v[j]; }
  for (int off = 32; off; off >>= 1) { s += __shfl_xor(s, off); s2 += __shfl_xor(s2, off); }
  float mean = s * (1.f / 512.f);
  float var = s2 * (1.f / 512.f) - mean * mean;
  float rs = rsqrtf(var + 1e-5f);
  const float* gp = g + (lane << 3);
  const float* bp = bta + (lane << 3);
  u16x8 pb, pn;
#pragma unroll
  for (int j = 0; j < 8; ++j) {
    pb[j] = f2h(v[j]);
    pn[j] = f2h((v[j] - mean) * rs * gp[j] + bp[j]);
  }
  *(u16x8*)(xb + (size_t)row * 512 + (lane << 3)) = pb;
  *(u16x8*)(xn + (size_t)row * 512 + (lane << 3)) = pn;
}

// ---------------- LayerNorm (f16 in) -> f16 out -----------------------------
__global__ __launch_bounds__(256) void ln_b16(const u16* __restrict__ xin,
    const float* __restrict__ g, const float* __restrict__ bta,
    u16* __restrict__ xout) {
  int row = (blockIdx.x << 2) + (threadIdx.x >> 6);
  int lane = threadIdx.x & 63;
  f16x8 u = *(const f16x8*)(xin + (size_t)row * 512 + (lane << 3));
  float v[8];
#pragma unroll
  for (int j = 0; j < 8; ++j) v[j] = (float)u[j];
  float s = 0.f, s2 = 0.f;
#pragma unroll
  for (int j = 0; j < 8; ++j) { s += v[j]; s2 += v[j] * v[j]; }
  for (int off = 32; off; off >>= 1) { s += __shfl_xor(s, off); s2 += __shfl_xor(s2, off); }
  float mean = s * (1.f / 512.f);
  float var = s2 * (1.f / 512.f) - mean * mean;
  float rs = rsqrtf(var + 1e-5f);
  const float* gp = g + (lane << 3);
  const float* bp = bta + (lane << 3);
  u16x8 pn;
#pragma unroll
  for (int j = 0; j < 8; ++j) pn[j] = f2h((v[j] - mean) * rs * gp[j] + bp[j]);
  *(u16x8*)(xout + (size_t)row * 512 + (lane << 3)) = pn;
}

// ---------------- GEMM: C(MxN f16) = A(Mx512 f16) * Bt(Nx512 f16)^T ---------
// 128x128 tile, BK=64, 4 waves, SERIAL staging, 34.8KB LDS -> 4 blocks/CU.
// R16 closed the ledger: this config beats all pipelined variants at K=512
// (serial 4blk=110-123us < dbuf-BK32 125 < 8w-serial 126 < dbuf 138 < depth2
// 157). Pre-swizzled conflict-free fragment reads, LDS-staged coalesced Cs
// epilogue, XCD swizzle.
template <bool GELU>
__global__ __launch_bounds__(256, 4) void gemm_bt(const u16* __restrict__ A,
    const u16* __restrict__ Bt, u16* __restrict__ C,
    const float* __restrict__ bias, int M, int N) {
  __shared__ __align__(16) char smem[34816];  // As 16K | Bs 16K ; Cs 34.8K union
  u16* Cs = (u16*)smem;                       // 128 x 136 f16, after final barrier
  constexpr int LDC = 136;
  int tid = threadIdx.x;
  int w = tid >> 6, lane = tid & 63;
  int nwg = gridDim.x * gridDim.y;
  int wg = blockIdx.x + gridDim.x * blockIdx.y;
  int swz = (wg & 7) * (nwg >> 3) + (wg >> 3);
  int m0 = (swz / gridDim.x) << 7, n0 = (swz % gridDim.x) << 7;
  int wm = (w & 1) << 6, wn = (w >> 1) << 6;
  f32x4 acc[4][4] = {};
  const int grow = tid >> 3;                  // 0..31 (row base within sweep)
  const int gcol = (((tid & 7) ^ (grow & 7)) << 3);  // pre-swizzled global col
  for (int kt = 0; kt < 8; ++kt) {
    __syncthreads();                          // buffer free (prev compute done)
    {
      u16* dA = (u16*)smem;
      u16* dB = (u16*)(smem + 16384);
#pragma unroll
      for (int s = 0; s < 4; ++s) {
        const u16* gA = A + (size_t)(m0 + grow + (s << 5)) * 512 + (kt << 6) + gcol;
        __builtin_amdgcn_global_load_lds(
            (const __attribute__((address_space(1))) u32*)gA,
            (__attribute__((address_space(3))) u32*)(dA + tid * 8 + (s << 11)), 16, 0, 0);
      }
#pragma unroll
      for (int s = 0; s < 4; ++s) {
        const u16* gB = Bt + (size_t)(n0 + grow + (s << 5)) * 512 + (kt << 6) + gcol;
        __builtin_amdgcn_global_load_lds(
            (const __attribute__((address_space(1))) u32*)gB,
            (__attribute__((address_space(3))) u32*)(dB + tid * 8 + (s << 11)), 16, 0, 0);
      }
    }
    asm volatile("s_waitcnt vmcnt(0)" ::: "memory");
    __syncthreads();
    const u16* As = (const u16*)smem;
    const u16* Bs = (const u16*)(smem + 16384);
#pragma unroll
    for (int kk = 0; kk < 2; ++kk) {
      int slot_w = (kk << 2) + (lane >> 4);   // 16B slot 0..7
      f16x8 af[4], bfr[4];
#pragma unroll
      for (int mi = 0; mi < 4; ++mi) {
        int rr = wm + (mi << 4) + (lane & 15);
        af[mi] = *(const f16x8*)(As + rr * 64 + ((slot_w ^ (rr & 7)) << 3));
      }
#pragma unroll
      for (int ni = 0; ni < 4; ++ni) {
        int rr = wn + (ni << 4) + (lane & 15);
        bfr[ni] = *(const f16x8*)(Bs + rr * 64 + ((slot_w ^ (rr & 7)) << 3));
      }
#pragma unroll
      for (int mi = 0; mi < 4; ++mi)
#pragma unroll
        for (int ni = 0; ni < 4; ++ni)
          acc[mi][ni] = __builtin_amdgcn_mfma_f32_16x16x32_f16(af[mi], bfr[ni], acc[mi][ni], 0, 0, 0);
    }
  }
  __syncthreads();                            // all waves done with As/Bs
  int cr = (lane >> 4) << 2, cc = lane & 15;
#pragma unroll
  for (int mi = 0; mi < 4; ++mi) {
#pragma unroll
    for (int ni = 0; ni < 4; ++ni) {
      float bv = 0.f;
      if (GELU) bv = bias[n0 + wn + (ni << 4) + cc];
#pragma unroll
      for (int j = 0; j < 4; ++j) {
        float v = acc[mi][ni][j];
        if (GELU) { v += bv; v = 0.5f * v * (1.f + erff(v * 0.70710678118f)); }
        Cs[(wm + (mi << 4) + cr + j) * LDC + wn + (ni << 4) + cc] = f2h(v);
      }
    }
  }
  __syncthreads();
  int r = tid >> 1, hc = (tid & 1) << 6;
  u16* crow = C + (size_t)(m0 + r) * N + n0 + hc;
  const u16* srow = Cs + r * LDC + hc;
#pragma unroll
  for (int i = 0; i < 8; ++i)
    *(u16x8*)(crow + (i << 3)) = *(const u16x8*)(srow + (i << 3));
}

// ---------------- attention: G batches/block, packed-f16 math ---------------
// attn12/attn7: DBUF G=4 (R15-validated). attn25: single-buffer G=1 (2048
// blocks/slice, 3 blk/CU LDS-capped — max independent blocks, finest balance).
// PMODE: 0 out=xb+o/(3s) | 1 out+=o/(3s) | 2 p=o/s | 3 p+=o/s | 4 out=xb+(p+o/s)/3
template <int NKV, int PMODE, int MINW, int G, bool DBUF>
__global__ __launch_bounds__(512, MINW) void attn(const u16* __restrict__ Q,
    const u16* __restrict__ KV, const u16* __restrict__ xb,
    float* __restrict__ out, u16* __restrict__ p) {
  constexpr int ELEMS = NKV * 1024;
  __shared__ __align__(16) u16 KVl[(DBUF ? 2 : 1)][ELEMS];
  int tid = threadIdx.x;
  int b0 = blockIdx.x * G;
  int h = tid >> 6, r = tid & 63, n = r >> 1, half = r & 1;
  int dbase = (h << 6) + (half << 5);
  bool act = (n < 25);
  f16x8 q8[4];
  if constexpr (DBUF) {
    if (act) {
      const u16* qr = Q + (size_t)(b0 * 25 + n) * 512 + dbase;
#pragma unroll
      for (int i = 0; i < 4; ++i) q8[i] = *(const f16x8*)(qr + (i << 3));
    }
    __builtin_amdgcn_sched_barrier(0);
    const u16* src = KV + (size_t)b0 * ELEMS;
    for (int e = tid * 8; e < ELEMS; e += 4096)
      __builtin_amdgcn_global_load_lds(
          (const __attribute__((address_space(1))) u32*)(src + e),
          (__attribute__((address_space(3))) u32*)(KVl[0] + e), 16, 0, 0);
    asm volatile("s_waitcnt vmcnt(0)" ::: "memory");
    __syncthreads();
  }
  for (int t = 0; t < G; ++t) {
    const u16* KVc = KVl[DBUF ? (t & 1) : 0];
    int b = b0 + t;
    size_t rowoff = (size_t)(b * 25 + n) * 512 + dbase;
    f16x8 pv16[4];
    f16x8 xv16[4];
    float4 ov[8];
    if (act) {
      if (PMODE == 3 || PMODE == 4) {
        const u16* prow = p + rowoff;
#pragma unroll
        for (int i = 0; i < 4; ++i) pv16[i] = *(const f16x8*)(prow + (i << 3));
      }
      if (PMODE == 0 || PMODE == 4) {
        const u16* xrow = xb + rowoff;
#pragma unroll
        for (int i = 0; i < 4; ++i) xv16[i] = *(const f16x8*)(xrow + (i << 3));
      }
      if (PMODE == 1) {
        const float* orow = out + rowoff;
#pragma unroll
        for (int i = 0; i < 8; ++i) ov[i] = *(const float4*)(orow + (i << 2));
      }
    }
    f16x8 qn[4];
    if constexpr (DBUF) {
      if (act && t + 1 < G) {
        const u16* qr = Q + (size_t)((b + 1) * 25 + n) * 512 + dbase;
#pragma unroll
        for (int i = 0; i < 4; ++i) qn[i] = *(const f16x8*)(qr + (i << 3));
      }
      __builtin_amdgcn_sched_barrier(0);
      if (t + 1 < G) {
        const u16* src = KV + (size_t)(b + 1) * ELEMS;
        u16* dst = KVl[(t + 1) & 1];
        for (int e = tid * 8; e < ELEMS; e += 4096)
          __builtin_amdgcn_global_load_lds(
              (const __attribute__((address_space(1))) u32*)(src + e),
              (__attribute__((address_space(3))) u32*)(dst + e), 16, 0, 0);
      }
    } else {
      if (act) {
        const u16* qr = Q + (size_t)(b * 25 + n) * 512 + dbase;
#pragma unroll
        for (int i = 0; i < 4; ++i) q8[i] = *(const f16x8*)(qr + (i << 3));
      }
      const u16* src = KV + (size_t)b * ELEMS;
      for (int e = tid * 8; e < ELEMS; e += 4096)
        __builtin_amdgcn_global_load_lds(
            (const __attribute__((address_space(1))) u32*)(src + e),
            (__attribute__((address_space(3))) u32*)(KVl[0] + e), 16, 0, 0);
      asm volatile("s_waitcnt vmcnt(0)" ::: "memory");
      __syncthreads();
    }
    if (act) {
      const f16x2* q2 = (const f16x2*)q8;
      float s[NKV];
      float mx = -1e30f;
#pragma unroll
      for (int m = 0; m < NKV; ++m) {
        const u16* kr = KVc + m * 1024 + dbase;
        f16x2 a0 = {(f16)0.f, (f16)0.f}, a1 = a0;
#pragma unroll
        for (int i = 0; i < 4; ++i) {
          f16x8 kv = *(const f16x8*)(kr + (i << 3));
          const f16x2* k2 = (const f16x2*)&kv;
          a0 += q2[i * 4 + 0] * k2[0];
          a1 += q2[i * 4 + 1] * k2[1];
          a0 += q2[i * 4 + 2] * k2[2];
          a1 += q2[i * 4 + 3] * k2[3];
        }
        f16x2 at = a0 + a1;
        float d = (float)at[0] + (float)at[1];
        d += __shfl_xor(d, 1);
        s[m] = d * 0.125f;
        mx = fmaxf(mx, s[m]);
      }
      float sum = 0.f;
#pragma unroll
      for (int m = 0; m < NKV; ++m) { s[m] = __expf(s[m] - mx); sum += s[m]; }
      f16x8 o8[4] = {};
#pragma unroll
      for (int m = 0; m < NKV; ++m) {
        f16 ah = (f16)s[m];
        f16x8 av = {ah, ah, ah, ah, ah, ah, ah, ah};
        const u16* vr = KVc + m * 1024 + 512 + dbase;
#pragma unroll
        for (int i = 0; i < 4; ++i) {
          f16x8 vv = *(const f16x8*)(vr + (i << 3));
          o8[i] += vv * av;
        }
      }
      if (PMODE == 0 || PMODE == 1) {
        float sc = (1.f / sum) * (1.f / 3.f);
        float* orow = out + rowoff;
#pragma unroll
        for (int i = 0; i < 4; ++i) {
#pragma unroll
          for (int j = 0; j < 8; j += 4) {
            float4 rr;
            if (PMODE == 0) {
              rr.x = (float)o8[i][j + 0] * sc + (float)xv16[i][j + 0];
              rr.y = (float)o8[i][j + 1] * sc + (float)xv16[i][j + 1];
              rr.z = (float)o8[i][j + 2] * sc + (float)xv16[i][j + 2];
              rr.w = (float)o8[i][j + 3] * sc + (float)xv16[i][j + 3];
            } else {
              float4 pv = ov[i * 2 + (j >> 2)];
              rr.x = (float)o8[i][j + 0] * sc + pv.x;
              rr.y = (float)o8[i][j + 1] * sc + pv.y;
              rr.z = (float)o8[i][j + 2] * sc + pv.z;
              rr.w = (float)o8[i][j + 3] * sc + pv.w;
            }
            *(float4*)(orow + (i << 3) + j) = rr;
          }
        }
      } else if (PMODE == 2 || PMODE == 3) {
        float sc = 1.f / sum;
        u16* prow = p + rowoff;
#pragma unroll
        for (int i = 0; i < 4; ++i) {
          u16x8 pk;
#pragma unroll
          for (int j = 0; j < 8; ++j) {
            float v = (float)o8[i][j] * sc;
            if (PMODE == 3) v += (float)pv16[i][j];
            pk[j] = f2h(v);
          }
          *(u16x8*)(prow + (i << 3)) = pk;
        }
      } else {                                 // PMODE 4
        float sc = 1.f / sum;
        float* orow = out + rowoff;
#pragma unroll
        for (int i = 0; i < 4; ++i) {
#pragma unroll
          for (int j = 0; j < 8; j += 4) {
            float4 rr;
            rr.x = (float)xv16[i][j + 0] + ((float)pv16[i][j + 0] + (float)o8[i][j + 0] * sc) * (1.f / 3.f);
            rr.y = (float)xv16[i][j + 1] + ((float)pv16[i][j + 1] + (float)o8[i][j + 1] * sc) * (1.f / 3.f);
            rr.z = (float)xv16[i][j + 2] + ((float)pv16[i][j + 2] + (float)o8[i][j + 2] * sc) * (1.f / 3.f);
            rr.w = (float)xv16[i][j + 3] + ((float)pv16[i][j + 3] + (float)o8[i][j + 3] * sc) * (1.f / 3.f);
            *(float4*)(orow + (i << 3) + j) = rr;
          }
        }
      }
    }
    if constexpr (DBUF) {
      asm volatile("s_waitcnt vmcnt(0)" ::: "memory");
      __syncthreads();
#pragma unroll
      for (int i = 0; i < 4; ++i) q8[i] = qn[i];
    } else {
      if (t + 1 < G) __syncthreads();
    }
  }
}

// ---------------- pool: fc2 + softmax + S^T * l_feat ------------------------
template <int NIN, int NOUT>
__global__ __launch_bounds__(256) void pool(const u16* __restrict__ h,
    const u16* __restrict__ lf, const float* __restrict__ w2,
    const float* __restrict__ b2, u16* __restrict__ lout) {
  __shared__ __align__(16) float W2l[1024 * NOUT];
  __shared__ __align__(16) u16 Xl[NIN * 512];
  __shared__ __align__(16) float Sl[NIN * NOUT];
  int b = blockIdx.x, tid = threadIdx.x;
  for (int e = tid; e < 1024 * NOUT; e += 256) W2l[e] = w2[e];
  for (int e = tid * 8; e < NIN * 512; e += 2048)
    *(u16x8*)(Xl + e) = *(const u16x8*)(lf + (size_t)b * NIN * 512 + e);
  __syncthreads();
  if (tid < NIN * 8) {
    int nn = tid >> 3, sub = tid & 7;
    float pl[NOUT] = {};
    const u16* hr = h + (size_t)(b * NIN + nn) * 1024;
    for (int cc = 0; cc < 128; ++cc) {
      int c = sub + (cc << 3);
      float hv = h2f(hr[c]);
#pragma unroll
      for (int s2 = 0; s2 < NOUT; ++s2) pl[s2] += hv * W2l[c * NOUT + s2];
    }
#pragma unroll
    for (int s2 = 0; s2 < NOUT; ++s2) {
      pl[s2] += __shfl_down(pl[s2], 4, 8);
      pl[s2] += __shfl_down(pl[s2], 2, 8);
      pl[s2] += __shfl_down(pl[s2], 1, 8);
    }
    if (sub == 0) {
      float mx = -1e30f;
#pragma unroll
      for (int s2 = 0; s2 < NOUT; ++s2) { pl[s2] += b2[s2]; mx = fmaxf(mx, pl[s2]); }
      float sum = 0.f;
#pragma unroll
      for (int s2 = 0; s2 < NOUT; ++s2) { pl[s2] = __expf(pl[s2] - mx); sum += pl[s2]; }
      float inv = 1.f / sum;
#pragma unroll
      for (int s2 = 0; s2 < NOUT; ++s2) Sl[nn * NOUT + s2] = pl[s2] * inv;
    }
  }
  __syncthreads();
  int c0 = tid << 1;
#pragma unroll
  for (int s2 = 0; s2 < NOUT; ++s2) {
    float a0 = 0.f, a1 = 0.f;
#pragma unroll
    for (int nn = 0; nn < NIN; ++nn) {
      float wv = Sl[nn * NOUT + s2];
      a0 += wv * h2f(Xl[nn * 512 + c0]);
      a1 += wv * h2f(Xl[nn * 512 + c0 + 1]);
    }
    u32 pk = (u32)f2h(a0) | ((u32)f2h(a1) << 16);
    *(u32*)(lout + (size_t)(b * NOUT + s2) * 512 + c0) = pk;
  }
}

// ---------------- launcher ---------------------------------------------------
extern "C" void kernel_launch(void* const* d_in, const int* in_sizes, int n_in,
                              void* d_out, int out_size, void* d_ws, size_t ws_size,
                              hipStream_t stream) {
  const float* src = (const float*)d_in[0];
  const float* g    = (const float*)d_in[2];
  const float* bt   = (const float*)d_in[3];
  const float* Wq   = (const float*)d_in[4];
  const float* Wk   = (const float*)d_in[5];
  const float* Wv   = (const float*)d_in[6];
  const float* f0w  = (const float*)d_in[7];
  const float* f0b  = (const float*)d_in[8];
  const float* f0w2 = (const float*)d_in[9];
  const float* f0b2 = (const float*)d_in[10];
  const float* f1w  = (const float*)d_in[11];
  const float* f1b  = (const float*)d_in[12];
  const float* f1w2 = (const float*)d_in[13];
  const float* f1b2 = (const float*)d_in[14];
  float* out = (float*)d_out;
  char* ws = (char*)d_ws;

  // base layout (bytes), peak 503 MB (validated); pbuf extension to 632 MB
  u16* wt  = (u16*)(ws + 0);
  u16* xn  = (u16*)(ws + 6815744);
  u16* xb  = (u16*)(ws + 111673344);
  u16* qb  = (u16*)(ws + 216530944);
  u16* B1  = (u16*)(ws + 321388544);
  u16* l1  = (u16*)(ws + 426246144);
  u16* kn1 = (u16*)(ws + 476577792);
  u16* l2  = qb;
  u16* kn2 = qb + 14680064;
  bool bigws = ws_size >= 640000000ull;
  u16* pbuf = (u16*)(ws + 526909440);

  prep_w<<<13312, 256, 0, stream>>>(Wq, Wk, Wv, f0w, f1w, wt);
  ln_f32<<<25600, 256, 0, stream>>>(src, g, bt, xn, xb);

  // scale 0
  gemm_bt<false><<<dim3(4, 800), 256, 0, stream>>>(xn, wt, qb, nullptr, 102400, 512);
  for (int s = 0; s < 2; ++s) {
    size_t ro = (size_t)s * 51200;
    gemm_bt<false><<<dim3(8, 400), 256, 0, stream>>>(xn + ro * 512, wt + 786432, B1, nullptr, 51200, 1024);
    if (bigws)
      attn<25, 2, 3, 1, false><<<2048, 512, 0, stream>>>(qb + ro * 512, B1, xb + ro * 512, out + ro * 512, pbuf + ro * 512);
    else
      attn<25, 0, 3, 1, false><<<2048, 512, 0, stream>>>(qb + ro * 512, B1, xb + ro * 512, out + ro * 512, pbuf);
  }

  // pool 0
  for (int s = 0; s < 2; ++s) {
    size_t ro = (size_t)s * 51200;
    gemm_bt<true><<<dim3(8, 400), 256, 0, stream>>>(xb + ro * 512, wt + 2359296, B1, f0b, 51200, 1024);
    pool<25, 12><<<2048, 256, 0, stream>>>(B1, xb + ro * 512, f0w2, f0b2, l1 + (size_t)s * 2048 * 12 * 512);
  }
  ln_b16<<<12288, 256, 0, stream>>>(l1, g, bt, kn1);

  // scale 1
  gemm_bt<false><<<dim3(4, 800), 256, 0, stream>>>(xn, wt + 262144, qb, nullptr, 102400, 512);
  gemm_bt<false><<<dim3(8, 384), 256, 0, stream>>>(kn1, wt + 786432 + 524288, B1, nullptr, 49152, 1024);
  if (bigws)
    attn<12, 3, 3, 4, true><<<1024, 512, 0, stream>>>(qb, B1, xb, out, pbuf);
  else
    attn<12, 1, 3, 4, true><<<1024, 512, 0, stream>>>(qb, B1, xb, out, pbuf);

  // pool 1
  gemm_bt<true><<<dim3(8, 384), 256, 0, stream>>>(l1, wt + 2883584, B1, f1b, 49152, 1024);
  pool<12, 7><<<4096, 256, 0, stream>>>(B1, l1, f1w2, f1b2, l2);
  ln_b16<<<7168, 256, 0, stream>>>(l2, g, bt, kn2);

  // scale 2 (KV gemm before Q gemm: kn2 lives in qb region)
  gemm_bt<false><<<dim3(8, 224), 256, 0, stream>>>(kn2, wt + 786432 + 1048576, B1, nullptr, 28672, 1024);
  gemm_bt<false><<<dim3(4, 800), 256, 0, stream>>>(xn, wt + 524288, qb, nullptr, 102400, 512);
  if (bigws)
    attn<7, 4, 3, 4, true><<<1024, 512, 0, stream>>>(qb, B1, xb, out, pbuf);
  else
    attn<7, 1, 3, 4, true><<<1024, 512, 0, stream>>>(qb, B1, xb, out, pbuf);
}